// Round 11
// baseline (1274.621 us; speedup 1.0000x reference)
//
#include <hip/hip_runtime.h>

typedef unsigned int uint;
typedef unsigned short ushort;
typedef __attribute__((ext_vector_type(8))) short bf16x8;
typedef __attribute__((ext_vector_type(4))) float f32x4;

#define N_NODES 2000
#define N_EDGES 32000
#define WNUM 2304
#define NBLK 768
#define MAGIC 0x5CA1AB1E

// ---------- ws layout (float element offsets) ----------
constexpr size_t OFF_AGG0 = 0;        // 2000*32
constexpr size_t OFF_AGG1 = 64000;    // 2000*48
constexpr size_t OFF_DEN  = 160000;   // 2000*4
constexpr size_t OFF_W2T  = 168004;   // ushort[2][2304][64] = 147456 floats
constexpr size_t OFF_QT0  = 315460;   // 2000*32
constexpr size_t OFF_QT1  = 379460;   // 2000*48
constexpr size_t OFF_CNT  = 475460;   // 2000 int
constexpr size_t OFF_EORD = 477460;   // 32000 int
constexpr size_t OFF_BAR  = 509460;   // 18 ints: cnt[8], flag[8], ready, wctr

__device__ __forceinline__ float b2f(ushort u){ union{uint i; float f;}x; x.i=((uint)u)<<16; return x.f; }
__device__ __forceinline__ float lo16(uint w){ union{uint u; float f;}x; x.u=w<<16; return x.f; }
__device__ __forceinline__ float hi16(uint w){ union{uint u; float f;}x; x.u=w&0xFFFF0000u; return x.f; }
__device__ __forceinline__ ushort f2b(float f){
  union{float f; uint u;}x; x.f=f;
  uint r = (x.u + 0x7FFFu + ((x.u>>16)&1u)) >> 16;
  return (ushort)r;
}
__device__ __forceinline__ float siluf(float x){ return x / (1.f + __expf(-x)); }

template<bool F32>
__device__ __forceinline__ float ldf(const void* p, int i){
  if (F32) return ((const float*)p)[i];
  return b2f(((const ushort*)p)[i]);
}

// ---------- device-scope grid barrier (all NBLK blocks resident by launch_bounds) ----------
__device__ __forceinline__ void gridbar(int* bar, int k){
  __syncthreads();
  if (threadIdx.x == 0){
    __threadfence();
    int prev = __hip_atomic_fetch_add(&bar[k], 1, __ATOMIC_ACQ_REL, __HIP_MEMORY_SCOPE_AGENT);
    if (prev == NBLK-1)
      __hip_atomic_store(&bar[8+k], 1, __ATOMIC_RELEASE, __HIP_MEMORY_SCOPE_AGENT);
    else
      while (__hip_atomic_load(&bar[8+k], __ATOMIC_ACQUIRE, __HIP_MEMORY_SCOPE_AGENT) == 0)
        __builtin_amdgcn_s_sleep(1);
    __threadfence();
  }
  __syncthreads();
}

// ---------- edge Smem (r9 layout) ----------
struct Smem {
  ushort hidA[2][32][72];
  float fssT[32][36];
  float fvvT[16][36];
  float sslT[32][36];
  float vshT[16][3][36];
  float sh1T[3][36];
  float cont[4][32][21];
  int   dstL[32];
};                              // 38,960 B

#define SRAW_BYTES 39424

// ---------- edge unit (r9 edge_body, verbatim, geb param) ----------
template<bool F32>
__device__ void edge_unit(
    const void* __restrict__ nf,  const int* __restrict__ eidx,
    const int* __restrict__ eord, int geb,
    const void* __restrict__ esh, const void* __restrict__ emb,
    const void* __restrict__ Wk1, const void* __restrict__ bk1, const void* __restrict__ bk2,
    const void* __restrict__ Wv1, const void* __restrict__ bv1, const void* __restrict__ bv2,
    const ushort* __restrict__ W2T,
    const float* __restrict__ qt0g, const float* __restrict__ qt1g,
    float* __restrict__ agg0, float* __restrict__ agg1, float* __restrict__ denom,
    Smem& sm){
  const int t  = threadIdx.x;
  const int hw = t >> 5;
  const int r  = t & 31;

  // Phase A
  #pragma unroll 1
  for (int e=0; e<4; ++e){
    const int le = hw*4+e;
    const int ge = eord[geb+le];
    const int src = eidx[ge], d = eidx[N_EDGES+ge];
    const float sh0 = ldf<F32>(esh, ge*4+0);
    const float s1a = ldf<F32>(esh, ge*4+1), s1b = ldf<F32>(esh, ge*4+2), s1c = ldf<F32>(esh, ge*4+3);
    if (r == 0) sm.dstL[le] = d;
    if (r < 3) sm.sh1T[r][le] = (r==0)? s1a : (r==1)? s1b : s1c;
    float sv = ldf<F32>(nf, src*80 + r);
    sm.sslT[r][le] = sv;
    sm.fssT[r][le] = sv * sh0;
    if (r < 16){
      float v0 = ldf<F32>(nf, src*80+32+r*3+0);
      float v1 = ldf<F32>(nf, src*80+32+r*3+1);
      float v2 = ldf<F32>(nf, src*80+32+r*3+2);
      sm.vshT[r][0][le] = v0*sh0; sm.vshT[r][1][le] = v1*sh0; sm.vshT[r][2][le] = v2*sh0;
      sm.fvvT[r][le] = (v0*s1a + v1*s1b + v2*s1c) * 0.5773502691896258f;
    }
  }

  // Phase B
  #pragma unroll 1
  for (int e=0; e<4; ++e){
    const int le = hw*4+e;
    const int ge = eord[geb+le];
    float em[16];
    if (F32){
      const float4* p = (const float4*)((const float*)emb + ge*16);
      float4 a=p[0], b=p[1], c=p[2], d4=p[3];
      em[0]=a.x; em[1]=a.y; em[2]=a.z; em[3]=a.w;
      em[4]=b.x; em[5]=b.y; em[6]=b.z; em[7]=b.w;
      em[8]=c.x; em[9]=c.y; em[10]=c.z; em[11]=c.w;
      em[12]=d4.x; em[13]=d4.y; em[14]=d4.z; em[15]=d4.w;
    } else {
      const uint4* p = (const uint4*)((const ushort*)emb + ge*16);
      uint4 a=p[0], b=p[1];
      em[0]=lo16(a.x); em[1]=hi16(a.x); em[2]=lo16(a.y); em[3]=hi16(a.y);
      em[4]=lo16(a.z); em[5]=hi16(a.z); em[6]=lo16(a.w); em[7]=hi16(a.w);
      em[8]=lo16(b.x); em[9]=hi16(b.x); em[10]=lo16(b.y); em[11]=hi16(b.y);
      em[12]=lo16(b.z); em[13]=hi16(b.z); em[14]=lo16(b.w); em[15]=hi16(b.w);
    }
    #pragma unroll
    for (int cc=0; cc<2; ++cc){
      const int c = r + cc*32;
      float ak = ldf<F32>(bk1, c), av = ldf<F32>(bv1, c);
      #pragma unroll
      for (int b=0; b<16; ++b){
        ak += em[b] * ldf<F32>(Wk1, b*64 + c);
        av += em[b] * ldf<F32>(Wv1, b*64 + c);
      }
      sm.hidA[0][le][c] = f2b(siluf(ak));
      sm.hidA[1][le][c] = f2b(siluf(av));
    }
  }
  __syncthreads();

  // Phase C
  const int h = t >> 6;
  const int lane = t & 63, q = lane >> 4, n = lane & 15;
  const ushort* w2tk = W2T;
  const ushort* w2tv = W2T + 147456;

  bf16x8 af[2][2][2];
  #pragma unroll
  for (int kv=0; kv<2; ++kv)
    #pragma unroll
    for (int Mt=0; Mt<2; ++Mt)
      #pragma unroll
      for (int kh=0; kh<2; ++kh)
        af[kv][Mt][kh] = *(const bf16x8*)&sm.hidA[kv][Mt*16+n][kh*32 + q*8];

  float aK0[2][4], aV0[2][4], aPK[2][4], aPV[2][4], aWK[3][2][4], aWV[3][2][4];
  #pragma unroll
  for (int Mt=0; Mt<2; ++Mt)
    #pragma unroll
    for (int z=0; z<4; ++z){
      aK0[Mt][z]=0.f; aV0[Mt][z]=0.f; aPK[Mt][z]=0.f; aPV[Mt][z]=0.f;
      aWK[0][Mt][z]=0.f; aWK[1][Mt][z]=0.f; aWK[2][Mt][z]=0.f;
      aWV[0][Mt][z]=0.f; aWV[1][Mt][z]=0.f; aWV[2][Mt][z]=0.f;
    }

  #pragma unroll 2
  for (int tl=0; tl<24; ++tl){
    const size_t tb = ((size_t)((h*36+tl)*16 + n))*64 + q*8;
    bf16x8 bk0 = *(const bf16x8*)(w2tk + tb), bk1f = *(const bf16x8*)(w2tk + tb + 32);
    bf16x8 bv0 = *(const bf16x8*)(w2tv + tb), bv1f = *(const bf16x8*)(w2tv + tb + 32);
    const int j = h*576 + tl*16 + n;
    const float bbk = ldf<F32>(bk2, j), bbv = ldf<F32>(bv2, j);
    const bool ss = (tl < 16);
    const int u = ss ? (tl*2 + (n>>3)) : ((tl-16)*2 + (n>>3));
    #pragma unroll
    for (int Mt=0; Mt<2; ++Mt){
      f32x4 fv = ss ? *(const f32x4*)&sm.fssT[u][Mt*16+q*4]
                    : *(const f32x4*)&sm.fvvT[u][Mt*16+q*4];
      f32x4 ck = {bbk,bbk,bbk,bbk};
      ck = __builtin_amdgcn_mfma_f32_16x16x32_bf16(af[0][Mt][0], bk0, ck, 0,0,0);
      ck = __builtin_amdgcn_mfma_f32_16x16x32_bf16(af[0][Mt][1], bk1f, ck, 0,0,0);
      f32x4 cv = {bbv,bbv,bbv,bbv};
      cv = __builtin_amdgcn_mfma_f32_16x16x32_bf16(af[1][Mt][0], bv0, cv, 0,0,0);
      cv = __builtin_amdgcn_mfma_f32_16x16x32_bf16(af[1][Mt][1], bv1f, cv, 0,0,0);
      #pragma unroll
      for (int z=0; z<4; ++z){ aK0[Mt][z] += ck[z]*fv[z]; aV0[Mt][z] += cv[z]*fv[z]; }
    }
  }
  #pragma unroll 2
  for (int tl=24; tl<32; ++tl){
    const size_t tb = ((size_t)((h*36+tl)*16 + n))*64 + q*8;
    bf16x8 bk0 = *(const bf16x8*)(w2tk + tb), bk1f = *(const bf16x8*)(w2tk + tb + 32);
    bf16x8 bv0 = *(const bf16x8*)(w2tv + tb), bv1f = *(const bf16x8*)(w2tv + tb + 32);
    const int j = h*576 + tl*16 + n;
    const float bbk = ldf<F32>(bk2, j), bbv = ldf<F32>(bv2, j);
    const int u = (tl-24)*4 + (n>>2);
    #pragma unroll
    for (int Mt=0; Mt<2; ++Mt){
      f32x4 fv = *(const f32x4*)&sm.sslT[u][Mt*16+q*4];
      f32x4 ck = {bbk,bbk,bbk,bbk};
      ck = __builtin_amdgcn_mfma_f32_16x16x32_bf16(af[0][Mt][0], bk0, ck, 0,0,0);
      ck = __builtin_amdgcn_mfma_f32_16x16x32_bf16(af[0][Mt][1], bk1f, ck, 0,0,0);
      f32x4 cv = {bbv,bbv,bbv,bbv};
      cv = __builtin_amdgcn_mfma_f32_16x16x32_bf16(af[1][Mt][0], bv0, cv, 0,0,0);
      cv = __builtin_amdgcn_mfma_f32_16x16x32_bf16(af[1][Mt][1], bv1f, cv, 0,0,0);
      #pragma unroll
      for (int z=0; z<4; ++z){ aPK[Mt][z] += ck[z]*fv[z]; aPV[Mt][z] += cv[z]*fv[z]; }
    }
  }
  #pragma unroll 1
  for (int tl=32; tl<36; ++tl){
    const size_t tb = ((size_t)((h*36+tl)*16 + n))*64 + q*8;
    bf16x8 bk0 = *(const bf16x8*)(w2tk + tb), bk1f = *(const bf16x8*)(w2tk + tb + 32);
    bf16x8 bv0 = *(const bf16x8*)(w2tv + tb), bv1f = *(const bf16x8*)(w2tv + tb + 32);
    const int j = h*576 + tl*16 + n;
    const float bbk = ldf<F32>(bk2, j), bbv = ldf<F32>(bv2, j);
    const int u = (tl-32)*4 + (n>>2);
    #pragma unroll
    for (int Mt=0; Mt<2; ++Mt){
      f32x4 ck = {bbk,bbk,bbk,bbk};
      ck = __builtin_amdgcn_mfma_f32_16x16x32_bf16(af[0][Mt][0], bk0, ck, 0,0,0);
      ck = __builtin_amdgcn_mfma_f32_16x16x32_bf16(af[0][Mt][1], bk1f, ck, 0,0,0);
      f32x4 cv = {bbv,bbv,bbv,bbv};
      cv = __builtin_amdgcn_mfma_f32_16x16x32_bf16(af[1][Mt][0], bv0, cv, 0,0,0);
      cv = __builtin_amdgcn_mfma_f32_16x16x32_bf16(af[1][Mt][1], bv1f, cv, 0,0,0);
      #pragma unroll
      for (int i=0; i<3; ++i){
        f32x4 fv = *(const f32x4*)&sm.vshT[u][i][Mt*16+q*4];
        #pragma unroll
        for (int z=0; z<4; ++z){ aWK[i][Mt][z] += ck[z]*fv[z]; aWV[i][Mt][z] += cv[z]*fv[z]; }
      }
    }
  }

  #pragma unroll
  for (int Mt=0; Mt<2; ++Mt)
    #pragma unroll
    for (int z=0; z<4; ++z){
      aK0[Mt][z] += __shfl_xor(aK0[Mt][z], 8, 64);
      aV0[Mt][z] += __shfl_xor(aV0[Mt][z], 8, 64);
      aPK[Mt][z] += __shfl_xor(aPK[Mt][z], 4, 64);
      aPK[Mt][z] += __shfl_xor(aPK[Mt][z], 8, 64);
      aPV[Mt][z] += __shfl_xor(aPV[Mt][z], 4, 64);
      aPV[Mt][z] += __shfl_xor(aPV[Mt][z], 8, 64);
      #pragma unroll
      for (int i=0; i<3; ++i){
        aWK[i][Mt][z] += __shfl_xor(aWK[i][Mt][z], 4, 64);
        aWK[i][Mt][z] += __shfl_xor(aWK[i][Mt][z], 8, 64);
        aWV[i][Mt][z] += __shfl_xor(aWV[i][Mt][z], 4, 64);
        aWV[i][Mt][z] += __shfl_xor(aWV[i][Mt][z], 8, 64);
      }
    }

  // Phase D
  const float invfan = 0.14433756729740643f;
  int dn[2][4];
  #pragma unroll
  for (int Mt=0; Mt<2; ++Mt)
    #pragma unroll
    for (int z=0; z<4; ++z) dn[Mt][z] = sm.dstL[Mt*16 + q*4 + z];

  f32x4 s1v[3][2];
  #pragma unroll
  for (int i=0; i<3; ++i)
    #pragma unroll
    for (int Mt=0; Mt<2; ++Mt)
      s1v[i][Mt] = *(const f32x4*)&sm.sh1T[i][Mt*16+q*4];

  float lgp[2][4];
  #pragma unroll
  for (int Mt=0; Mt<2; ++Mt)
    #pragma unroll
    for (int z=0; z<4; ++z){
      float acc = 0.f;
      if (n < 8) acc = qt0g[dn[Mt][z]*32 + h*8 + n] * aK0[Mt][z];
      if (n < 4){
        float s = 0.f;
        #pragma unroll
        for (int i=0; i<3; ++i){
          float k1 = aPK[Mt][z]*s1v[i][Mt][z] + aWK[i][Mt][z];
          s += qt1g[dn[Mt][z]*48 + h*12 + n*3 + i] * k1;
        }
        acc += s * 0.5773502691896258f;
      }
      lgp[Mt][z] = acc;
    }
  #pragma unroll
  for (int Mt=0; Mt<2; ++Mt)
    #pragma unroll
    for (int z=0; z<4; ++z){
      lgp[Mt][z] += __shfl_xor(lgp[Mt][z], 1, 64);
      lgp[Mt][z] += __shfl_xor(lgp[Mt][z], 2, 64);
      lgp[Mt][z] += __shfl_xor(lgp[Mt][z], 4, 64);
      lgp[Mt][z] += __shfl_xor(lgp[Mt][z], 8, 64);
    }

  #pragma unroll
  for (int Mt=0; Mt<2; ++Mt)
    #pragma unroll
    for (int z=0; z<4; ++z){
      float lg = lgp[Mt][z] * invfan * 0.025f;
      lg = fminf(10.f, fmaxf(-10.f, lg));
      const float ex = __expf(lg - 10.0f);
      const int el = Mt*16 + q*4 + z;
      if (n == 0) sm.cont[h][el][0] = ex;
      if (n < 8)  sm.cont[h][el][1+n] = ex * aV0[Mt][z] * invfan;
      if (n < 4){
        #pragma unroll
        for (int i=0; i<3; ++i){
          float v1 = (aPV[Mt][z]*s1v[i][Mt][z] + aWV[i][Mt][z]) * invfan;
          sm.cont[h][el][9+n*3+i] = ex * v1;
        }
      }
    }
  __syncthreads();

  if (t < 84){
    const int h2 = t / 21, comp = t - h2*21;
    float acc = 0.f;
    #pragma unroll 1
    for (int e2=0; e2<32; ++e2){
      acc += sm.cont[h2][e2][comp];
      const int d2 = sm.dstL[e2];
      if (e2 == 31 || sm.dstL[e2+1] != d2){
        if (comp == 0)      atomicAdd(denom + d2*4  + h2, acc);
        else if (comp < 9)  atomicAdd(agg0  + d2*32 + h2*8  + (comp-1), acc);
        else                atomicAdd(agg1  + d2*48 + h2*12 + (comp-9), acc);
        acc = 0.f;
      }
    }
  }
}

// ---------- mega body ----------
template<bool F32>
__device__ void mega_body(
    const void* nf, const int* eidx, const void* esh, const void* emb,
    const void* Wq0, const void* Wq1, const void* Wk1, const void* bk1,
    const void* Wk2, const void* bk2, const void* Wv1, const void* bv1,
    const void* Wv2, const void* bv2, const void* Wd0, const void* Wd1,
    const void* Wo0, const void* Wo1, const void* Wf10, const void* Wf11,
    const void* Wf20, const void* Wf21, void* out,
    ushort* W2T, float* qt0, float* qt1,
    float* agg0, float* agg1, float* denom,
    int* cnt, int* eord, int* bar,
    unsigned char* sraw, int* s_unit){
  const int bid = blockIdx.x, t = threadIdx.x;
  int* ready = bar + 16;
  int* wctr  = bar + 17;

  // init barrier state (ws is 0xAA-poisoned before every launch)
  if (bid == 0 && t == 0){
    #pragma unroll
    for (int i=0; i<16; ++i) bar[i] = 0;
    *wctr = 0;
    __threadfence();
    __hip_atomic_store(ready, MAGIC, __ATOMIC_RELEASE, __HIP_MEMORY_SCOPE_AGENT);
  }
  if (t == 0)
    while (__hip_atomic_load(ready, __ATOMIC_ACQUIRE, __HIP_MEMORY_SCOPE_AGENT) != MAGIC)
      __builtin_amdgcn_s_sleep(1);
  __syncthreads();

  // ---- S0a: transpose | zero | node_q ----
  if (bid < 72){
    ushort (*tile)[66] = (ushort(*)[66])sraw;
    const int mat = bid / 36, jt = bid - mat*36;
    const void* W = mat ? Wv2 : Wk2;
    const int j0 = jt*64;
    const int jo = t & 63, cb = t >> 6;
    #pragma unroll
    for (int k=0; k<16; ++k){
      const int c = cb + k*4;
      tile[c][jo] = F32 ? f2b(((const float*)W)[(size_t)c*WNUM + j0 + jo])
                        : ((const ushort*)W)[(size_t)c*WNUM + j0 + jo];
    }
    __syncthreads();
    const int jl = t >> 2, c0 = (t & 3)*16;
    ushort* dst = W2T + (size_t)mat*147456 + (size_t)(j0+jl)*64 + c0;
    #pragma unroll
    for (int k=0; k<16; ++k) dst[k] = tile[c0+k][jl];
  } else if (bid < 104){
    const int zb = bid - 72;
    float4* az = (float4*)agg0;
    for (int idx = zb*256 + t; idx < 42000; idx += 32*256)
      az[idx] = make_float4(0.f,0.f,0.f,0.f);
    for (int idx = zb*256 + t; idx < N_NODES; idx += 32*256)
      cnt[idx] = 0;
  } else if (bid < 136){
    const int nb = bid - 104;
    const int n0 = nb*64;
    float* nfL = (float*)sraw;            // 64 nodes x 80 feats
    for (int idx = t; idx < 64*80; idx += 256){
      int nn = n0 + idx/80;
      nfL[idx] = (nn < N_NODES) ? ldf<F32>(nf, nn*80 + (idx - (idx/80)*80)) : 0.f;
    }
    __syncthreads();
    const int tid = nb*256 + t;
    if (tid < N_NODES*4){
      const int nn = tid >> 2, h = tid & 3;
      const float* S = nfL + (nn - n0)*80;
      float q0[8];
      #pragma unroll
      for (int w=0; w<8; ++w){
        float a = 0.f;
        #pragma unroll
        for (int u=0; u<32; ++u) a += S[u]*ldf<F32>(Wq0, h*256 + u*8 + w);
        q0[w] = a * 0.17677669529663687f;
      }
      #pragma unroll
      for (int vv=0; vv<8; ++vv){
        float a = 0.f;
        #pragma unroll
        for (int u=0; u<8; ++u) a += q0[u]*ldf<F32>(Wd0, u*8+vv);
        qt0[nn*32 + h*8 + vv] = a;
      }
      float q1[12];
      #pragma unroll
      for (int w=0; w<4; ++w)
        #pragma unroll
        for (int i=0; i<3; ++i){
          float a = 0.f;
          #pragma unroll
          for (int u=0; u<16; ++u) a += S[32+u*3+i]*ldf<F32>(Wq1, h*64 + u*4 + w);
          q1[w*3+i] = a * 0.25f;
        }
      #pragma unroll
      for (int vv=0; vv<4; ++vv)
        #pragma unroll
        for (int i=0; i<3; ++i){
          float a = 0.f;
          #pragma unroll
          for (int u=0; u<4; ++u) a += q1[u*3+i]*ldf<F32>(Wd1, u*4+vv);
          qt1[nn*48 + h*12 + vv*3 + i] = a;
        }
    }
  }
  gridbar(bar, 0);

  // ---- S0b: degree count ----
  { int e = bid*256 + t; if (e < N_EDGES) atomicAdd(cnt + eidx[N_EDGES + e], 1); }
  gridbar(bar, 1);

  // ---- S1: scan (block 0) ----
  if (bid == 0){
    int* ls = (int*)sraw;
    const int base = t*8;
    int v[8]; int s = 0;
    #pragma unroll
    for (int k=0; k<8; ++k){ int idx = base+k; v[k] = (idx < N_NODES) ? cnt[idx] : 0; s += v[k]; }
    ls[t] = s; __syncthreads();
    for (int off=1; off<256; off<<=1){
      int x = (t >= off) ? ls[t-off] : 0;
      __syncthreads();
      ls[t] += x;
      __syncthreads();
    }
    int ex = ls[t] - s;
    #pragma unroll
    for (int k=0; k<8; ++k){ int idx = base+k; if (idx < N_NODES){ int c = v[k]; cnt[idx] = ex; ex += c; } }
  }
  gridbar(bar, 2);

  // ---- S2: scatter ----
  { int e = bid*256 + t;
    if (e < N_EDGES){ int p = atomicAdd(cnt + eidx[N_EDGES + e], 1); eord[p] = e; } }
  gridbar(bar, 3);

  // ---- S3: edge units via dynamic queue ----
  Smem& sm = *(Smem*)sraw;
  for (;;){
    __syncthreads();
    if (t == 0) *s_unit = atomicAdd(wctr, 1);
    __syncthreads();
    const int u = *s_unit;
    if (u >= N_EDGES/32) break;
    edge_unit<F32>(nf, eidx, eord, u*32, esh, emb, Wk1, bk1, bk2, Wv1, bv1, bv2,
                   W2T, qt0, qt1, agg0, agg1, denom, sm);
  }
  gridbar(bar, 4);

  // ---- S4: node_out (4 groups of 64 threads, node = bid + 768*g) ----
  {
    const int g = t >> 6, tl = t & 63;
    const int n = bid + NBLK*g;
    const bool act = (n < N_NODES);
    float* B = (float*)sraw + g*304;
    float* ag0 = B; float* ag1 = B+32; float* adiv = B+80;
    float* x0s = B+84; float* x1s = B+116; float* a0s = B+164;
    float* f1s = B+228; float* coefs = B+276;
    if (act && tl < 4) adiv[tl] = 1.f / (denom[n*4+tl] + 1e-12f);
    __syncthreads();
    if (act && tl < 32) ag0[tl] = agg0[n*32+tl] * adiv[tl>>3];
    if (act && tl < 48) ag1[tl] = agg1[n*48+tl] * adiv[tl/12];
    __syncthreads();
    if (act && tl < 32){
      float o = 0.f;
      #pragma unroll
      for (int k=0; k<32; ++k) o += ag0[k]*ldf<F32>(Wo0, k*32+tl);
      x0s[tl] = ldf<F32>(nf, n*80+tl) + o*0.17677669529663687f;
    }
    if (act && tl < 48){
      int w = tl/3, i = tl - w*3;
      float o = 0.f;
      #pragma unroll
      for (int u=0; u<16; ++u) o += ag1[u*3+i]*ldf<F32>(Wo1, u*16+w);
      x1s[tl] = ldf<F32>(nf, n*80+32+tl) + o*0.25f;
    }
    __syncthreads();
    if (act){
      float f0 = 0.f;
      #pragma unroll
      for (int u=0; u<32; ++u) f0 += x0s[u]*ldf<F32>(Wf10, u*64+tl);
      a0s[tl] = siluf(f0*0.17677669529663687f);
    }
    if (act && tl < 48){
      int w = tl/3, i = tl - w*3;
      float f1 = 0.f;
      #pragma unroll
      for (int u=0; u<16; ++u) f1 += x1s[u*3+i]*ldf<F32>(Wf11, u*16+w);
      f1s[tl] = f1*0.25f;
    }
    __syncthreads();
    if (act && tl < 16){
      float a = f1s[tl*3], b = f1s[tl*3+1], c = f1s[tl*3+2];
      float nrm = sqrtf(a*a+b*b+c*c);
      float safe = fmaxf(nrm, 1e-8f);
      coefs[tl] = (nrm < 1e-8f) ? 0.f : siluf(nrm)/safe;
    }
    __syncthreads();
    if (act && tl < 32){
      float gg = 0.f;
      #pragma unroll
      for (int u=0; u<64; ++u) gg += a0s[u]*ldf<F32>(Wf20, u*32+tl);
      float val = x0s[tl] + gg*0.125f;
      if (F32) ((float*)out)[n*80+tl] = val; else ((ushort*)out)[n*80+tl] = f2b(val);
    }
    if (act && tl < 48){
      int w = tl/3, i = tl - w*3;
      float gg = 0.f;
      #pragma unroll
      for (int u=0; u<16; ++u) gg += coefs[u]*f1s[u*3+i]*ldf<F32>(Wf21, u*16+w);
      float val = x1s[tl] + gg*0.25f;
      if (F32) ((float*)out)[n*80+32+tl] = val; else ((ushort*)out)[n*80+32+tl] = f2b(val);
    }
  }
}

__global__ __launch_bounds__(256, 3) void mega_kernel(
    const void* nf, const int* eidx, const void* esh, const void* emb,
    const void* Wq0, const void* Wq1, const void* Wk1, const void* bk1,
    const void* Wk2, const void* bk2, const void* Wv1, const void* bv1,
    const void* Wv2, const void* bv2, const void* Wd0, const void* Wd1,
    const void* Wo0, const void* Wo1, const void* Wf10, const void* Wf11,
    const void* Wf20, const void* Wf21, void* out,
    ushort* W2T, float* qt0, float* qt1,
    float* agg0, float* agg1, float* denom,
    int* cnt, int* eord, int* bar){
  __shared__ __align__(16) unsigned char sraw[SRAW_BYTES];
  __shared__ int s_unit;
  __shared__ int s_cnt;
  // dtype probe (per block, same data -> same result for all blocks)
  if (threadIdx.x == 0) s_cnt = 0;
  __syncthreads();
  {
    uint u = ((const ushort*)nf)[threadIdx.x * 2];
    uint ex = (u >> 7) & 0xFFu;
    if (ex >= 0xA0u) atomicAdd(&s_cnt, 1);
  }
  __syncthreads();
  const bool F32 = (s_cnt >= 20);
  if (F32)
    mega_body<true >(nf,eidx,esh,emb,Wq0,Wq1,Wk1,bk1,Wk2,bk2,Wv1,bv1,Wv2,bv2,Wd0,Wd1,
                     Wo0,Wo1,Wf10,Wf11,Wf20,Wf21,out,W2T,qt0,qt1,agg0,agg1,denom,cnt,eord,bar,sraw,&s_unit);
  else
    mega_body<false>(nf,eidx,esh,emb,Wq0,Wq1,Wk1,bk1,Wk2,bk2,Wv1,bv1,Wv2,bv2,Wd0,Wd1,
                     Wo0,Wo1,Wf10,Wf11,Wf20,Wf21,out,W2T,qt0,qt1,agg0,agg1,denom,cnt,eord,bar,sraw,&s_unit);
}

extern "C" void kernel_launch(void* const* d_in, const int* in_sizes, int n_in,
                              void* d_out, int out_size, void* d_ws, size_t ws_size,
                              hipStream_t stream){
  const void* nf   = d_in[0];
  const int*  eidx = (const int*)d_in[1];
  const void* esh  = d_in[2];
  const void* emb  = d_in[3];
  const void* Wq0  = d_in[4];
  const void* Wq1  = d_in[5];
  const void* Wk1  = d_in[6];
  const void* bk1  = d_in[7];
  const void* Wk2  = d_in[8];
  const void* bk2  = d_in[9];
  const void* Wv1  = d_in[10];
  const void* bv1  = d_in[11];
  const void* Wv2  = d_in[12];
  const void* bv2  = d_in[13];
  const void* Wd0  = d_in[14];
  const void* Wd1  = d_in[15];
  const void* Wo0  = d_in[16];
  const void* Wo1  = d_in[17];
  const void* Wf10 = d_in[18];
  const void* Wf11 = d_in[19];
  const void* Wf20 = d_in[20];
  const void* Wf21 = d_in[21];
  float* ws = (float*)d_ws;

  float* agg0  = ws + OFF_AGG0;
  float* agg1  = ws + OFF_AGG1;
  float* denom = ws + OFF_DEN;
  ushort* W2T  = (ushort*)(ws + OFF_W2T);
  float* qt0   = ws + OFF_QT0;
  float* qt1   = ws + OFF_QT1;
  int*   cnt   = (int*)(ws + OFF_CNT);
  int*   eord  = (int*)(ws + OFF_EORD);
  int*   bar   = (int*)(ws + OFF_BAR);

  mega_kernel<<<NBLK, 256, 0, stream>>>(nf, eidx, esh, emb, Wq0, Wq1, Wk1, bk1,
                                        Wk2, bk2, Wv1, bv1, Wv2, bv2, Wd0, Wd1,
                                        Wo0, Wo1, Wf10, Wf11, Wf20, Wf21, d_out,
                                        W2T, qt0, qt1, agg0, agg1, denom,
                                        cnt, eord, bar);
}

// Round 13
// 239.318 us; speedup vs baseline: 5.3261x; 5.3261x over previous
//
#include <hip/hip_runtime.h>

typedef unsigned int uint;
typedef unsigned short ushort;
typedef __attribute__((ext_vector_type(8))) short bf16x8;
typedef __attribute__((ext_vector_type(4))) float f32x4;

#define N_NODES 2000
#define N_EDGES 32000
#define WNUM 2304

// ---------- ws layout (float element offsets) ----------
// [agg0 | agg1 | den | cnt] contiguous -> one memset zeroes all four.
constexpr size_t OFF_AGG0 = 0;        // 2000*32
constexpr size_t OFF_AGG1 = 64000;    // 2000*48
constexpr size_t OFF_DEN  = 160000;   // 2000*4
constexpr size_t OFF_CNT  = 168000;   // 2000 int
constexpr size_t OFF_FLAG = 170000;   // 1 int
constexpr size_t OFF_W2T  = 170004;   // ushort[2][2304][64] = 147456 floats
constexpr size_t OFF_QT0  = 317460;   // 2000*32
constexpr size_t OFF_QT1  = 381460;   // 2000*48
constexpr size_t OFF_EORD = 477460;   // 32000 int

__device__ __forceinline__ float b2f(ushort u){ union{uint i; float f;}x; x.i=((uint)u)<<16; return x.f; }
__device__ __forceinline__ float lo16(uint w){ union{uint u; float f;}x; x.u=w<<16; return x.f; }
__device__ __forceinline__ float hi16(uint w){ union{uint u; float f;}x; x.u=w&0xFFFF0000u; return x.f; }
__device__ __forceinline__ ushort f2b(float f){
  union{float f; uint u;}x; x.f=f;
  uint r = (x.u + 0x7FFFu + ((x.u>>16)&1u)) >> 16;
  return (ushort)r;
}
__device__ __forceinline__ float siluf(float x){ return x / (1.f + __expf(-x)); }

template<bool F32>
__device__ __forceinline__ float ldf(const void* p, int i){
  if (F32) return ((const float*)p)[i];
  return b2f(((const ushort*)p)[i]);
}
__device__ __forceinline__ float ldfr(const void* p, int i, bool f32){
  return f32 ? ((const float*)p)[i] : b2f(((const ushort*)p)[i]);
}

// ---------- K0 body: W2 transpose + LDS-staged node_q + degree count ----------
// blocks 0..71: transpose | 72..103: node_q (64 nodes/block) | 104..228: cnt
// cnt[] was zeroed by the stream-ordered memset before this dispatch.
template<bool F32>
__device__ void prep_body(
    const void* __restrict__ nf, const int* __restrict__ eidx,
    const void* __restrict__ Wk2, const void* __restrict__ Wv2,
    const void* __restrict__ Wq0, const void* __restrict__ Wq1,
    const void* __restrict__ Wd0, const void* __restrict__ Wd1,
    ushort* __restrict__ W2T, float* __restrict__ qt0, float* __restrict__ qt1,
    int* __restrict__ cnt){
  const int t = threadIdx.x;
  const int bid = blockIdx.x;

  if (bid < 72){
    // 64(j) x 64(c) tile transpose: W[c][j] -> W2T[mat][j][c], bf16 out
    __shared__ ushort tile[64][66];
    const int mat = bid / 36, jt = bid - mat*36;
    const void* W = mat ? Wv2 : Wk2;
    const int j0 = jt*64;
    const int jo = t & 63, cb = t >> 6;
    #pragma unroll
    for (int k=0; k<16; ++k){
      const int c = cb + k*4;
      tile[c][jo] = F32 ? f2b(((const float*)W)[(size_t)c*WNUM + j0 + jo])
                        : ((const ushort*)W)[(size_t)c*WNUM + j0 + jo];
    }
    __syncthreads();
    const int jl = t >> 2, c0 = (t & 3)*16;
    ushort* dst = W2T + (size_t)mat*147456 + (size_t)(j0+jl)*64 + c0;
    #pragma unroll
    for (int k=0; k<16; ++k) dst[k] = tile[c0+k][jl];
  } else if (bid < 104){
    // node_q for 64 nodes, all operands staged in LDS (kills latency serialization)
    __shared__ float nfL[64][80];     // 20480 B
    __shared__ float wq0L[1024], wq1L[256], wd0L[64], wd1L[16];
    const int nb = bid - 72, n0 = nb*64;
    for (int idx=t; idx<64*80; idx+=256){
      const int nn = n0 + idx/80;
      nfL[idx/80][idx%80] = (nn < N_NODES) ? ldf<F32>(nf, nn*80 + idx%80) : 0.f;
    }
    for (int idx=t; idx<1024; idx+=256) wq0L[idx] = ldf<F32>(Wq0, idx);
    if (t < 256) wq1L[t] = ldf<F32>(Wq1, t);
    if (t < 64)  wd0L[t] = ldf<F32>(Wd0, t);
    if (t < 16)  wd1L[t] = ldf<F32>(Wd1, t);
    __syncthreads();
    const int nl = t >> 2, h = t & 3;
    const int nn = n0 + nl;
    if (nn < N_NODES){
      const float* S = &nfL[nl][0];
      float q0[8];
      #pragma unroll
      for (int w=0; w<8; ++w){
        float a = 0.f;
        #pragma unroll
        for (int u=0; u<32; ++u) a += S[u]*wq0L[h*256 + u*8 + w];
        q0[w] = a * 0.17677669529663687f;   // 1/sqrt(32)
      }
      #pragma unroll
      for (int vv=0; vv<8; ++vv){
        float a = 0.f;
        #pragma unroll
        for (int u=0; u<8; ++u) a += q0[u]*wd0L[u*8+vv];
        qt0[nn*32 + h*8 + vv] = a;
      }
      float q1[12];
      #pragma unroll
      for (int w=0; w<4; ++w)
        #pragma unroll
        for (int i=0; i<3; ++i){
          float a = 0.f;
          #pragma unroll
          for (int u=0; u<16; ++u) a += S[32+u*3+i]*wq1L[h*64 + u*4 + w];
          q1[w*3+i] = a * 0.25f;            // 1/sqrt(16)
        }
      #pragma unroll
      for (int vv=0; vv<4; ++vv)
        #pragma unroll
        for (int i=0; i<3; ++i){
          float a = 0.f;
          #pragma unroll
          for (int u=0; u<4; ++u) a += q1[u*3+i]*wd1L[u*4+vv];
          qt1[nn*48 + h*12 + vv*3 + i] = a;
        }
    }
  } else {
    // degree count (cnt pre-zeroed by memset)
    const int e = (bid-104)*256 + t;
    if (e < N_EDGES) atomicAdd(cnt + eidx[N_EDGES + e], 1);
  }
}

__global__ __launch_bounds__(256) void prep_kernel(
    const void* nf, const int* eidx,
    const void* Wk2, const void* Wv2,
    const void* Wq0, const void* Wq1,
    const void* Wd0, const void* Wd1,
    ushort* W2T, float* qt0, float* qt1,
    int* cnt, int* flag){
  __shared__ int s_cnt;
  const int t = threadIdx.x;
  if (t == 0) s_cnt = 0;
  __syncthreads();
  {
    uint u = ((const ushort*)nf)[t*2];
    uint ex = (u >> 7) & 0xFFu;
    if (ex >= 0xA0u) atomicAdd(&s_cnt, 1);
  }
  __syncthreads();
  const bool F32 = (s_cnt >= 20);
  if (blockIdx.x == 0 && t == 0) *flag = F32 ? 1 : 0;
  if (F32) prep_body<true >(nf, eidx, Wk2, Wv2, Wq0, Wq1, Wd0, Wd1, W2T, qt0, qt1, cnt);
  else     prep_body<false>(nf, eidx, Wk2, Wv2, Wq0, Wq1, Wd0, Wd1, W2T, qt0, qt1, cnt);
}

// ---------- K1: exclusive scan over cnt (1 block) ----------
__global__ __launch_bounds__(256) void scan_kernel(int* __restrict__ cnt){
  __shared__ int ls[256];
  const int t = threadIdx.x;
  const int base = t*8;
  int v[8]; int s = 0;
  #pragma unroll
  for (int k=0; k<8; ++k){ int idx = base+k; v[k] = (idx < N_NODES) ? cnt[idx] : 0; s += v[k]; }
  ls[t] = s; __syncthreads();
  for (int off=1; off<256; off<<=1){
    int x = (t >= off) ? ls[t-off] : 0;
    __syncthreads();
    ls[t] += x;
    __syncthreads();
  }
  int ex = ls[t] - s;
  #pragma unroll
  for (int k=0; k<8; ++k){ int idx = base+k; if (idx < N_NODES){ int c = v[k]; cnt[idx] = ex; ex += c; } }
}

// ---------- K2: scatter (dst-sorted edge order) ----------
__global__ __launch_bounds__(256) void scat_kernel(const int* __restrict__ eidx,
                                                   int* __restrict__ cnt, int* __restrict__ eord){
  int e = blockIdx.x*256 + threadIdx.x;
  if (e < N_EDGES){
    int p = atomicAdd(cnt + eidx[N_EDGES + e], 1);
    eord[p] = e;
  }
}

// ---------- K3: fused edge kernel (r9 verbatim) ----------
struct Smem {
  ushort hidA[2][32][72];
  float fssT[32][36];
  float fvvT[16][36];
  float sslT[32][36];
  float vshT[16][3][36];
  float sh1T[3][36];
  float cont[4][32][21];
  int   dstL[32];
};                              // 38,960 B

template<bool F32>
__device__ void edge_body(
    const void* __restrict__ nf,  const int* __restrict__ eidx,
    const int* __restrict__ eord,
    const void* __restrict__ esh, const void* __restrict__ emb,
    const void* __restrict__ Wk1, const void* __restrict__ bk1, const void* __restrict__ bk2,
    const void* __restrict__ Wv1, const void* __restrict__ bv1, const void* __restrict__ bv2,
    const ushort* __restrict__ W2T,
    const float* __restrict__ qt0g, const float* __restrict__ qt1g,
    float* __restrict__ agg0, float* __restrict__ agg1, float* __restrict__ denom,
    Smem& sm){
  const int t  = threadIdx.x;
  const int hw = t >> 5;
  const int r  = t & 31;
  const int geb = blockIdx.x*32;

  // Phase A
  #pragma unroll 1
  for (int e=0; e<4; ++e){
    const int le = hw*4+e;
    const int ge = eord[geb+le];
    const int src = eidx[ge], d = eidx[N_EDGES+ge];
    const float sh0 = ldf<F32>(esh, ge*4+0);
    const float s1a = ldf<F32>(esh, ge*4+1), s1b = ldf<F32>(esh, ge*4+2), s1c = ldf<F32>(esh, ge*4+3);
    if (r == 0) sm.dstL[le] = d;
    if (r < 3) sm.sh1T[r][le] = (r==0)? s1a : (r==1)? s1b : s1c;
    float sv = ldf<F32>(nf, src*80 + r);
    sm.sslT[r][le] = sv;
    sm.fssT[r][le] = sv * sh0;
    if (r < 16){
      float v0 = ldf<F32>(nf, src*80+32+r*3+0);
      float v1 = ldf<F32>(nf, src*80+32+r*3+1);
      float v2 = ldf<F32>(nf, src*80+32+r*3+2);
      sm.vshT[r][0][le] = v0*sh0; sm.vshT[r][1][le] = v1*sh0; sm.vshT[r][2][le] = v2*sh0;
      sm.fvvT[r][le] = (v0*s1a + v1*s1b + v2*s1c) * 0.5773502691896258f;
    }
  }

  // Phase B
  #pragma unroll 1
  for (int e=0; e<4; ++e){
    const int le = hw*4+e;
    const int ge = eord[geb+le];
    float em[16];
    if (F32){
      const float4* p = (const float4*)((const float*)emb + ge*16);
      float4 a=p[0], b=p[1], c=p[2], d4=p[3];
      em[0]=a.x; em[1]=a.y; em[2]=a.z; em[3]=a.w;
      em[4]=b.x; em[5]=b.y; em[6]=b.z; em[7]=b.w;
      em[8]=c.x; em[9]=c.y; em[10]=c.z; em[11]=c.w;
      em[12]=d4.x; em[13]=d4.y; em[14]=d4.z; em[15]=d4.w;
    } else {
      const uint4* p = (const uint4*)((const ushort*)emb + ge*16);
      uint4 a=p[0], b=p[1];
      em[0]=lo16(a.x); em[1]=hi16(a.x); em[2]=lo16(a.y); em[3]=hi16(a.y);
      em[4]=lo16(a.z); em[5]=hi16(a.z); em[6]=lo16(a.w); em[7]=hi16(a.w);
      em[8]=lo16(b.x); em[9]=hi16(b.x); em[10]=lo16(b.y); em[11]=hi16(b.y);
      em[12]=lo16(b.z); em[13]=hi16(b.z); em[14]=lo16(b.w); em[15]=hi16(b.w);
    }
    #pragma unroll
    for (int cc=0; cc<2; ++cc){
      const int c = r + cc*32;
      float ak = ldf<F32>(bk1, c), av = ldf<F32>(bv1, c);
      #pragma unroll
      for (int b=0; b<16; ++b){
        ak += em[b] * ldf<F32>(Wk1, b*64 + c);
        av += em[b] * ldf<F32>(Wv1, b*64 + c);
      }
      sm.hidA[0][le][c] = f2b(siluf(ak));
      sm.hidA[1][le][c] = f2b(siluf(av));
    }
  }
  __syncthreads();

  // Phase C
  const int h = t >> 6;
  const int lane = t & 63, q = lane >> 4, n = lane & 15;
  const ushort* w2tk = W2T;
  const ushort* w2tv = W2T + 147456;

  bf16x8 af[2][2][2];
  #pragma unroll
  for (int kv=0; kv<2; ++kv)
    #pragma unroll
    for (int Mt=0; Mt<2; ++Mt)
      #pragma unroll
      for (int kh=0; kh<2; ++kh)
        af[kv][Mt][kh] = *(const bf16x8*)&sm.hidA[kv][Mt*16+n][kh*32 + q*8];

  float aK0[2][4], aV0[2][4], aPK[2][4], aPV[2][4], aWK[3][2][4], aWV[3][2][4];
  #pragma unroll
  for (int Mt=0; Mt<2; ++Mt)
    #pragma unroll
    for (int z=0; z<4; ++z){
      aK0[Mt][z]=0.f; aV0[Mt][z]=0.f; aPK[Mt][z]=0.f; aPV[Mt][z]=0.f;
      aWK[0][Mt][z]=0.f; aWK[1][Mt][z]=0.f; aWK[2][Mt][z]=0.f;
      aWV[0][Mt][z]=0.f; aWV[1][Mt][z]=0.f; aWV[2][Mt][z]=0.f;
    }

  #pragma unroll 2
  for (int tl=0; tl<24; ++tl){
    const size_t tb = ((size_t)((h*36+tl)*16 + n))*64 + q*8;
    bf16x8 bk0 = *(const bf16x8*)(w2tk + tb), bk1f = *(const bf16x8*)(w2tk + tb + 32);
    bf16x8 bv0 = *(const bf16x8*)(w2tv + tb), bv1f = *(const bf16x8*)(w2tv + tb + 32);
    const int j = h*576 + tl*16 + n;
    const float bbk = ldf<F32>(bk2, j), bbv = ldf<F32>(bv2, j);
    const bool ss = (tl < 16);
    const int u = ss ? (tl*2 + (n>>3)) : ((tl-16)*2 + (n>>3));
    #pragma unroll
    for (int Mt=0; Mt<2; ++Mt){
      f32x4 fv = ss ? *(const f32x4*)&sm.fssT[u][Mt*16+q*4]
                    : *(const f32x4*)&sm.fvvT[u][Mt*16+q*4];
      f32x4 ck = {bbk,bbk,bbk,bbk};
      ck = __builtin_amdgcn_mfma_f32_16x16x32_bf16(af[0][Mt][0], bk0, ck, 0,0,0);
      ck = __builtin_amdgcn_mfma_f32_16x16x32_bf16(af[0][Mt][1], bk1f, ck, 0,0,0);
      f32x4 cv = {bbv,bbv,bbv,bbv};
      cv = __builtin_amdgcn_mfma_f32_16x16x32_bf16(af[1][Mt][0], bv0, cv, 0,0,0);
      cv = __builtin_amdgcn_mfma_f32_16x16x32_bf16(af[1][Mt][1], bv1f, cv, 0,0,0);
      #pragma unroll
      for (int z=0; z<4; ++z){ aK0[Mt][z] += ck[z]*fv[z]; aV0[Mt][z] += cv[z]*fv[z]; }
    }
  }
  #pragma unroll 2
  for (int tl=24; tl<32; ++tl){
    const size_t tb = ((size_t)((h*36+tl)*16 + n))*64 + q*8;
    bf16x8 bk0 = *(const bf16x8*)(w2tk + tb), bk1f = *(const bf16x8*)(w2tk + tb + 32);
    bf16x8 bv0 = *(const bf16x8*)(w2tv + tb), bv1f = *(const bf16x8*)(w2tv + tb + 32);
    const int j = h*576 + tl*16 + n;
    const float bbk = ldf<F32>(bk2, j), bbv = ldf<F32>(bv2, j);
    const int u = (tl-24)*4 + (n>>2);
    #pragma unroll
    for (int Mt=0; Mt<2; ++Mt){
      f32x4 fv = *(const f32x4*)&sm.sslT[u][Mt*16+q*4];
      f32x4 ck = {bbk,bbk,bbk,bbk};
      ck = __builtin_amdgcn_mfma_f32_16x16x32_bf16(af[0][Mt][0], bk0, ck, 0,0,0);
      ck = __builtin_amdgcn_mfma_f32_16x16x32_bf16(af[0][Mt][1], bk1f, ck, 0,0,0);
      f32x4 cv = {bbv,bbv,bbv,bbv};
      cv = __builtin_amdgcn_mfma_f32_16x16x32_bf16(af[1][Mt][0], bv0, cv, 0,0,0);
      cv = __builtin_amdgcn_mfma_f32_16x16x32_bf16(af[1][Mt][1], bv1f, cv, 0,0,0);
      #pragma unroll
      for (int z=0; z<4; ++z){ aPK[Mt][z] += ck[z]*fv[z]; aPV[Mt][z] += cv[z]*fv[z]; }
    }
  }
  #pragma unroll 1
  for (int tl=32; tl<36; ++tl){
    const size_t tb = ((size_t)((h*36+tl)*16 + n))*64 + q*8;
    bf16x8 bk0 = *(const bf16x8*)(w2tk + tb), bk1f = *(const bf16x8*)(w2tk + tb + 32);
    bf16x8 bv0 = *(const bf16x8*)(w2tv + tb), bv1f = *(const bf16x8*)(w2tv + tb + 32);
    const int j = h*576 + tl*16 + n;
    const float bbk = ldf<F32>(bk2, j), bbv = ldf<F32>(bv2, j);
    const int u = (tl-32)*4 + (n>>2);
    #pragma unroll
    for (int Mt=0; Mt<2; ++Mt){
      f32x4 ck = {bbk,bbk,bbk,bbk};
      ck = __builtin_amdgcn_mfma_f32_16x16x32_bf16(af[0][Mt][0], bk0, ck, 0,0,0);
      ck = __builtin_amdgcn_mfma_f32_16x16x32_bf16(af[0][Mt][1], bk1f, ck, 0,0,0);
      f32x4 cv = {bbv,bbv,bbv,bbv};
      cv = __builtin_amdgcn_mfma_f32_16x16x32_bf16(af[1][Mt][0], bv0, cv, 0,0,0);
      cv = __builtin_amdgcn_mfma_f32_16x16x32_bf16(af[1][Mt][1], bv1f, cv, 0,0,0);
      #pragma unroll
      for (int i=0; i<3; ++i){
        f32x4 fv = *(const f32x4*)&sm.vshT[u][i][Mt*16+q*4];
        #pragma unroll
        for (int z=0; z<4; ++z){ aWK[i][Mt][z] += ck[z]*fv[z]; aWV[i][Mt][z] += cv[z]*fv[z]; }
      }
    }
  }

  #pragma unroll
  for (int Mt=0; Mt<2; ++Mt)
    #pragma unroll
    for (int z=0; z<4; ++z){
      aK0[Mt][z] += __shfl_xor(aK0[Mt][z], 8, 64);
      aV0[Mt][z] += __shfl_xor(aV0[Mt][z], 8, 64);
      aPK[Mt][z] += __shfl_xor(aPK[Mt][z], 4, 64);
      aPK[Mt][z] += __shfl_xor(aPK[Mt][z], 8, 64);
      aPV[Mt][z] += __shfl_xor(aPV[Mt][z], 4, 64);
      aPV[Mt][z] += __shfl_xor(aPV[Mt][z], 8, 64);
      #pragma unroll
      for (int i=0; i<3; ++i){
        aWK[i][Mt][z] += __shfl_xor(aWK[i][Mt][z], 4, 64);
        aWK[i][Mt][z] += __shfl_xor(aWK[i][Mt][z], 8, 64);
        aWV[i][Mt][z] += __shfl_xor(aWV[i][Mt][z], 4, 64);
        aWV[i][Mt][z] += __shfl_xor(aWV[i][Mt][z], 8, 64);
      }
    }

  // Phase D
  const float invfan = 0.14433756729740643f;   // 1/sqrt(48)
  int dn[2][4];
  #pragma unroll
  for (int Mt=0; Mt<2; ++Mt)
    #pragma unroll
    for (int z=0; z<4; ++z) dn[Mt][z] = sm.dstL[Mt*16 + q*4 + z];

  f32x4 s1v[3][2];
  #pragma unroll
  for (int i=0; i<3; ++i)
    #pragma unroll
    for (int Mt=0; Mt<2; ++Mt)
      s1v[i][Mt] = *(const f32x4*)&sm.sh1T[i][Mt*16+q*4];

  float lgp[2][4];
  #pragma unroll
  for (int Mt=0; Mt<2; ++Mt)
    #pragma unroll
    for (int z=0; z<4; ++z){
      float acc = 0.f;
      if (n < 8) acc = qt0g[dn[Mt][z]*32 + h*8 + n] * aK0[Mt][z];
      if (n < 4){
        float s = 0.f;
        #pragma unroll
        for (int i=0; i<3; ++i){
          float k1 = aPK[Mt][z]*s1v[i][Mt][z] + aWK[i][Mt][z];
          s += qt1g[dn[Mt][z]*48 + h*12 + n*3 + i] * k1;
        }
        acc += s * 0.5773502691896258f;
      }
      lgp[Mt][z] = acc;
    }
  #pragma unroll
  for (int Mt=0; Mt<2; ++Mt)
    #pragma unroll
    for (int z=0; z<4; ++z){
      lgp[Mt][z] += __shfl_xor(lgp[Mt][z], 1, 64);
      lgp[Mt][z] += __shfl_xor(lgp[Mt][z], 2, 64);
      lgp[Mt][z] += __shfl_xor(lgp[Mt][z], 4, 64);
      lgp[Mt][z] += __shfl_xor(lgp[Mt][z], 8, 64);
    }

  #pragma unroll
  for (int Mt=0; Mt<2; ++Mt)
    #pragma unroll
    for (int z=0; z<4; ++z){
      float lg = lgp[Mt][z] * invfan * 0.025f;   // 1/(sqrt(80)*sqrt(20))
      lg = fminf(10.f, fmaxf(-10.f, lg));
      const float ex = __expf(lg - 10.0f);       // fixed softmax max = 10 (clipped logits)
      const int el = Mt*16 + q*4 + z;
      if (n == 0) sm.cont[h][el][0] = ex;
      if (n < 8)  sm.cont[h][el][1+n] = ex * aV0[Mt][z] * invfan;
      if (n < 4){
        #pragma unroll
        for (int i=0; i<3; ++i){
          float v1 = (aPV[Mt][z]*s1v[i][Mt][z] + aWV[i][Mt][z]) * invfan;
          sm.cont[h][el][9+n*3+i] = ex * v1;
        }
      }
    }
  __syncthreads();

  if (t < 84){
    const int h2 = t / 21, comp = t - h2*21;
    float acc = 0.f;
    #pragma unroll 1
    for (int e2=0; e2<32; ++e2){
      acc += sm.cont[h2][e2][comp];
      const int d2 = sm.dstL[e2];
      if (e2 == 31 || sm.dstL[e2+1] != d2){
        if (comp == 0)      atomicAdd(denom + d2*4  + h2, acc);
        else if (comp < 9)  atomicAdd(agg0  + d2*32 + h2*8  + (comp-1), acc);
        else                atomicAdd(agg1  + d2*48 + h2*12 + (comp-9), acc);
        acc = 0.f;
      }
    }
  }
}

__global__ __launch_bounds__(256) void edge_kernel(
    const void* nf, const int* eidx, const int* eord, const void* esh, const void* emb,
    const void* Wk1, const void* bk1, const void* bk2,
    const void* Wv1, const void* bv1, const void* bv2,
    const ushort* W2T, const float* qt0g, const float* qt1g,
    float* agg0, float* agg1, float* denom, const int* flag){
  __shared__ Smem sm;
  if (*flag)
    edge_body<true >(nf,eidx,eord,esh,emb,Wk1,bk1,bk2,Wv1,bv1,bv2,W2T,qt0g,qt1g,agg0,agg1,denom,sm);
  else
    edge_body<false>(nf,eidx,eord,esh,emb,Wk1,bk1,bk2,Wv1,bv1,bv2,W2T,qt0g,qt1g,agg0,agg1,denom,sm);
}

// ---------- K4: per-node output MLP ----------
__global__ __launch_bounds__(64) void node_out_kernel(
    const void* __restrict__ nf, const float* __restrict__ agg0r, const float* __restrict__ agg1r,
    const float* __restrict__ denom,
    const void* __restrict__ Wo0, const void* __restrict__ Wo1,
    const void* __restrict__ Wf10, const void* __restrict__ Wf11,
    const void* __restrict__ Wf20, const void* __restrict__ Wf21,
    void* __restrict__ out, const int* __restrict__ flag){
  __shared__ float ag0[32], ag1[48], adiv[4];
  __shared__ float x0s[32], x1s[48], a0s[64], f1s[48], coefs[16];
  const bool F32 = (*flag) != 0;
  const int n = blockIdx.x, t = threadIdx.x;
  if (t < 4) adiv[t] = 1.f / (denom[n*4+t] + 1e-12f);
  __syncthreads();
  if (t < 32) ag0[t] = agg0r[n*32+t] * adiv[t>>3];
  if (t < 48) ag1[t] = agg1r[n*48+t] * adiv[t/12];
  __syncthreads();
  if (t < 32){
    float o = 0.f;
    #pragma unroll
    for (int k=0; k<32; ++k) o += ag0[k]*ldfr(Wo0, k*32+t, F32);
    x0s[t] = ldfr(nf, n*80+t, F32) + o*0.17677669529663687f;
  }
  if (t < 48){
    int w = t/3, i = t - w*3;
    float o = 0.f;
    #pragma unroll
    for (int u=0; u<16; ++u) o += ag1[u*3+i]*ldfr(Wo1, u*16+w, F32);
    x1s[t] = ldfr(nf, n*80+32+t, F32) + o*0.25f;
  }
  __syncthreads();
  {
    float f0 = 0.f;
    #pragma unroll
    for (int u=0; u<32; ++u) f0 += x0s[u]*ldfr(Wf10, u*64+t, F32);
    a0s[t] = siluf(f0*0.17677669529663687f);
  }
  if (t < 48){
    int w = t/3, i = t - w*3;
    float f1 = 0.f;
    #pragma unroll
    for (int u=0; u<16; ++u) f1 += x1s[u*3+i]*ldfr(Wf11, u*16+w, F32);
    f1s[t] = f1*0.25f;
  }
  __syncthreads();
  if (t < 16){
    float a = f1s[t*3], b = f1s[t*3+1], c = f1s[t*3+2];
    float nrm = sqrtf(a*a+b*b+c*c);
    float safe = fmaxf(nrm, 1e-8f);
    coefs[t] = (nrm < 1e-8f) ? 0.f : siluf(nrm)/safe;
  }
  __syncthreads();
  if (t < 32){
    float g = 0.f;
    #pragma unroll
    for (int u=0; u<64; ++u) g += a0s[u]*ldfr(Wf20, u*32+t, F32);
    float val = x0s[t] + g*0.125f;
    if (F32) ((float*)out)[n*80+t] = val; else ((ushort*)out)[n*80+t] = f2b(val);
  }
  if (t < 48){
    int w = t/3, i = t - w*3;
    float g = 0.f;
    #pragma unroll
    for (int u=0; u<16; ++u) g += coefs[u]*f1s[u*3+i]*ldfr(Wf21, u*16+w, F32);
    float val = x1s[t] + g*0.25f;
    if (F32) ((float*)out)[n*80+32+t] = val; else ((ushort*)out)[n*80+32+t] = f2b(val);
  }
}

extern "C" void kernel_launch(void* const* d_in, const int* in_sizes, int n_in,
                              void* d_out, int out_size, void* d_ws, size_t ws_size,
                              hipStream_t stream){
  const void* nf   = d_in[0];
  const int*  eidx = (const int*)d_in[1];
  const void* esh  = d_in[2];
  const void* emb  = d_in[3];
  const void* Wq0  = d_in[4];
  const void* Wq1  = d_in[5];
  const void* Wk1  = d_in[6];
  const void* bk1  = d_in[7];
  const void* Wk2  = d_in[8];
  const void* bk2  = d_in[9];
  const void* Wv1  = d_in[10];
  const void* bv1  = d_in[11];
  const void* Wv2  = d_in[12];
  const void* bv2  = d_in[13];
  const void* Wd0  = d_in[14];
  const void* Wd1  = d_in[15];
  const void* Wo0  = d_in[16];
  const void* Wo1  = d_in[17];
  const void* Wf10 = d_in[18];
  const void* Wf11 = d_in[19];
  const void* Wf20 = d_in[20];
  const void* Wf21 = d_in[21];
  float* ws = (float*)d_ws;

  float* agg0  = ws + OFF_AGG0;
  float* agg1  = ws + OFF_AGG1;
  float* denom = ws + OFF_DEN;
  int*   cnt   = (int*)(ws + OFF_CNT);
  int*   flag  = (int*)(ws + OFF_FLAG);
  ushort* W2T  = (ushort*)(ws + OFF_W2T);
  float* qt0   = ws + OFF_QT0;
  float* qt1   = ws + OFF_QT1;
  int*   eord  = (int*)(ws + OFF_EORD);

  // zero agg0|agg1|den|cnt (contiguous 680 KB) — stream-ordered before prep
  hipMemsetAsync(agg0, 0, 170000*sizeof(float), stream);
  prep_kernel<<<229, 256, 0, stream>>>(nf, eidx, Wk2, Wv2, Wq0, Wq1, Wd0, Wd1,
                                       W2T, qt0, qt1, cnt, flag);
  scan_kernel<<<1, 256, 0, stream>>>(cnt);
  scat_kernel<<<125, 256, 0, stream>>>(eidx, cnt, eord);
  edge_kernel<<<N_EDGES/32, 256, 0, stream>>>(nf, eidx, eord, esh, emb,
                                              Wk1, bk1, bk2, Wv1, bv1, bv2,
                                              W2T, qt0, qt1,
                                              agg0, agg1, denom, flag);
  node_out_kernel<<<N_NODES, 64, 0, stream>>>(nf, agg0, agg1, denom,
                                              Wo0, Wo1, Wf10, Wf11, Wf20, Wf21, d_out, flag);
}

// Round 14
// 236.419 us; speedup vs baseline: 5.3914x; 1.0123x over previous
//
#include <hip/hip_runtime.h>

typedef unsigned int uint;
typedef unsigned short ushort;
typedef __attribute__((ext_vector_type(8))) short bf16x8;
typedef __attribute__((ext_vector_type(4))) float f32x4;

#define N_NODES 2000
#define N_EDGES 32000
#define WNUM 2304

// ---------- ws layout (float element offsets) ----------
constexpr size_t OFF_AGG0 = 0;        // 2000*32
constexpr size_t OFF_AGG1 = 64000;    // 2000*48
constexpr size_t OFF_DEN  = 160000;   // 2000*4
constexpr size_t OFF_CNT  = 168000;   // 2000 int
constexpr size_t OFF_FLAG = 170000;   // 1 int
constexpr size_t OFF_W2T  = 170004;   // ushort[2][2304][64] = 147456 floats
constexpr size_t OFF_QT0  = 317460;   // 2000*32
constexpr size_t OFF_QT1  = 381460;   // 2000*48
constexpr size_t OFF_EORD = 477460;   // 32000 int

__device__ __forceinline__ float b2f(ushort u){ union{uint i; float f;}x; x.i=((uint)u)<<16; return x.f; }
__device__ __forceinline__ float lo16(uint w){ union{uint u; float f;}x; x.u=w<<16; return x.f; }
__device__ __forceinline__ float hi16(uint w){ union{uint u; float f;}x; x.u=w&0xFFFF0000u; return x.f; }
__device__ __forceinline__ ushort f2b(float f){
  union{float f; uint u;}x; x.f=f;
  uint r = (x.u + 0x7FFFu + ((x.u>>16)&1u)) >> 16;
  return (ushort)r;
}
__device__ __forceinline__ float siluf(float x){ return x / (1.f + __expf(-x)); }

template<bool F32>
__device__ __forceinline__ float ldf(const void* p, int i){
  if (F32) return ((const float*)p)[i];
  return b2f(((const ushort*)p)[i]);
}
__device__ __forceinline__ float ldfr(const void* p, int i, bool f32){
  return f32 ? ((const float*)p)[i] : b2f(((const ushort*)p)[i]);
}

// ---------- K0 body: W2 transpose + LDS-staged node_q + degree count ----------
template<bool F32>
__device__ void prep_body(
    const void* __restrict__ nf, const int* __restrict__ eidx,
    const void* __restrict__ Wk2, const void* __restrict__ Wv2,
    const void* __restrict__ Wq0, const void* __restrict__ Wq1,
    const void* __restrict__ Wd0, const void* __restrict__ Wd1,
    ushort* __restrict__ W2T, float* __restrict__ qt0, float* __restrict__ qt1,
    int* __restrict__ cnt){
  const int t = threadIdx.x;
  const int bid = blockIdx.x;

  if (bid < 72){
    __shared__ ushort tile[64][66];
    const int mat = bid / 36, jt = bid - mat*36;
    const void* W = mat ? Wv2 : Wk2;
    const int j0 = jt*64;
    const int jo = t & 63, cb = t >> 6;
    #pragma unroll
    for (int k=0; k<16; ++k){
      const int c = cb + k*4;
      tile[c][jo] = F32 ? f2b(((const float*)W)[(size_t)c*WNUM + j0 + jo])
                        : ((const ushort*)W)[(size_t)c*WNUM + j0 + jo];
    }
    __syncthreads();
    const int jl = t >> 2, c0 = (t & 3)*16;
    ushort* dst = W2T + (size_t)mat*147456 + (size_t)(j0+jl)*64 + c0;
    #pragma unroll
    for (int k=0; k<16; ++k) dst[k] = tile[c0+k][jl];
  } else if (bid < 104){
    __shared__ float nfL[64][80];
    __shared__ float wq0L[1024], wq1L[256], wd0L[64], wd1L[16];
    const int nb = bid - 72, n0 = nb*64;
    for (int idx=t; idx<64*80; idx+=256){
      const int nn = n0 + idx/80;
      nfL[idx/80][idx%80] = (nn < N_NODES) ? ldf<F32>(nf, nn*80 + idx%80) : 0.f;
    }
    for (int idx=t; idx<1024; idx+=256) wq0L[idx] = ldf<F32>(Wq0, idx);
    if (t < 256) wq1L[t] = ldf<F32>(Wq1, t);
    if (t < 64)  wd0L[t] = ldf<F32>(Wd0, t);
    if (t < 16)  wd1L[t] = ldf<F32>(Wd1, t);
    __syncthreads();
    const int nl = t >> 2, h = t & 3;
    const int nn = n0 + nl;
    if (nn < N_NODES){
      const float* S = &nfL[nl][0];
      float q0[8];
      #pragma unroll
      for (int w=0; w<8; ++w){
        float a = 0.f;
        #pragma unroll
        for (int u=0; u<32; ++u) a += S[u]*wq0L[h*256 + u*8 + w];
        q0[w] = a * 0.17677669529663687f;   // 1/sqrt(32)
      }
      #pragma unroll
      for (int vv=0; vv<8; ++vv){
        float a = 0.f;
        #pragma unroll
        for (int u=0; u<8; ++u) a += q0[u]*wd0L[u*8+vv];
        qt0[nn*32 + h*8 + vv] = a;
      }
      float q1[12];
      #pragma unroll
      for (int w=0; w<4; ++w)
        #pragma unroll
        for (int i=0; i<3; ++i){
          float a = 0.f;
          #pragma unroll
          for (int u=0; u<16; ++u) a += S[32+u*3+i]*wq1L[h*64 + u*4 + w];
          q1[w*3+i] = a * 0.25f;            // 1/sqrt(16)
        }
      #pragma unroll
      for (int vv=0; vv<4; ++vv)
        #pragma unroll
        for (int i=0; i<3; ++i){
          float a = 0.f;
          #pragma unroll
          for (int u=0; u<4; ++u) a += q1[u*3+i]*wd1L[u*4+vv];
          qt1[nn*48 + h*12 + vv*3 + i] = a;
        }
    }
  } else {
    const int e = (bid-104)*256 + t;
    if (e < N_EDGES) atomicAdd(cnt + eidx[N_EDGES + e], 1);
  }
}

__global__ __launch_bounds__(256) void prep_kernel(
    const void* nf, const int* eidx,
    const void* Wk2, const void* Wv2,
    const void* Wq0, const void* Wq1,
    const void* Wd0, const void* Wd1,
    ushort* W2T, float* qt0, float* qt1,
    int* cnt, int* flag){
  __shared__ int s_cnt;
  const int t = threadIdx.x;
  if (t == 0) s_cnt = 0;
  __syncthreads();
  {
    uint u = ((const ushort*)nf)[t*2];
    uint ex = (u >> 7) & 0xFFu;
    if (ex >= 0xA0u) atomicAdd(&s_cnt, 1);
  }
  __syncthreads();
  const bool F32 = (s_cnt >= 20);
  if (blockIdx.x == 0 && t == 0) *flag = F32 ? 1 : 0;
  if (F32) prep_body<true >(nf, eidx, Wk2, Wv2, Wq0, Wq1, Wd0, Wd1, W2T, qt0, qt1, cnt);
  else     prep_body<false>(nf, eidx, Wk2, Wv2, Wq0, Wq1, Wd0, Wd1, W2T, qt0, qt1, cnt);
}

// ---------- K1: exclusive scan over cnt (1 block) ----------
__global__ __launch_bounds__(256) void scan_kernel(int* __restrict__ cnt){
  __shared__ int ls[256];
  const int t = threadIdx.x;
  const int base = t*8;
  int v[8]; int s = 0;
  #pragma unroll
  for (int k=0; k<8; ++k){ int idx = base+k; v[k] = (idx < N_NODES) ? cnt[idx] : 0; s += v[k]; }
  ls[t] = s; __syncthreads();
  for (int off=1; off<256; off<<=1){
    int x = (t >= off) ? ls[t-off] : 0;
    __syncthreads();
    ls[t] += x;
    __syncthreads();
  }
  int ex = ls[t] - s;
  #pragma unroll
  for (int k=0; k<8; ++k){ int idx = base+k; if (idx < N_NODES){ int c = v[k]; cnt[idx] = ex; ex += c; } }
}

// ---------- K2: scatter (dst-sorted edge order) ----------
__global__ __launch_bounds__(256) void scat_kernel(const int* __restrict__ eidx,
                                                   int* __restrict__ cnt, int* __restrict__ eord){
  int e = blockIdx.x*256 + threadIdx.x;
  if (e < N_EDGES){
    int p = atomicAdd(cnt + eidx[N_EDGES + e], 1);
    eord[p] = e;
  }
}

// ---------- K3: fused edge kernel (kv-outer, low-VGPR, cont overlaid) ----------
struct Smem {
  ushort hidA[2][32][72];       // 9216 B
  union {
    struct {
      float fssT[32][36];       // 4608
      float fvvT[16][36];       // 2304
      float sslT[32][36];       // 4608
    } f;                        // 11520
    float cont[4][32][21];      // 10752 — live only after Phase C (barrier-protected)
  } u;
  float vshT[16][3][36];        // 6912
  float sh1T[3][36];            // 432
  int   dstL[32];               // 128
};                              // 28,208 B -> 5 blocks/CU (LDS)

template<bool F32>
__device__ void edge_body(
    const void* __restrict__ nf,  const int* __restrict__ eidx,
    const int* __restrict__ eord,
    const void* __restrict__ esh, const void* __restrict__ emb,
    const void* __restrict__ Wk1, const void* __restrict__ bk1, const void* __restrict__ bk2,
    const void* __restrict__ Wv1, const void* __restrict__ bv1, const void* __restrict__ bv2,
    const ushort* __restrict__ W2T,
    const float* __restrict__ qt0g, const float* __restrict__ qt1g,
    float* __restrict__ agg0, float* __restrict__ agg1, float* __restrict__ denom,
    Smem& sm){
  const int t  = threadIdx.x;
  const int hw = t >> 5;
  const int r  = t & 31;
  const int geb = blockIdx.x*32;

  // Phase A
  #pragma unroll 1
  for (int e=0; e<4; ++e){
    const int le = hw*4+e;
    const int ge = eord[geb+le];
    const int src = eidx[ge], d = eidx[N_EDGES+ge];
    const float sh0 = ldf<F32>(esh, ge*4+0);
    const float s1a = ldf<F32>(esh, ge*4+1), s1b = ldf<F32>(esh, ge*4+2), s1c = ldf<F32>(esh, ge*4+3);
    if (r == 0) sm.dstL[le] = d;
    if (r < 3) sm.sh1T[r][le] = (r==0)? s1a : (r==1)? s1b : s1c;
    float sv = ldf<F32>(nf, src*80 + r);
    sm.u.f.sslT[r][le] = sv;
    sm.u.f.fssT[r][le] = sv * sh0;
    if (r < 16){
      float v0 = ldf<F32>(nf, src*80+32+r*3+0);
      float v1 = ldf<F32>(nf, src*80+32+r*3+1);
      float v2 = ldf<F32>(nf, src*80+32+r*3+2);
      sm.vshT[r][0][le] = v0*sh0; sm.vshT[r][1][le] = v1*sh0; sm.vshT[r][2][le] = v2*sh0;
      sm.u.f.fvvT[r][le] = (v0*s1a + v1*s1b + v2*s1c) * 0.5773502691896258f;
    }
  }

  // Phase B
  #pragma unroll 1
  for (int e=0; e<4; ++e){
    const int le = hw*4+e;
    const int ge = eord[geb+le];
    float em[16];
    if (F32){
      const float4* p = (const float4*)((const float*)emb + ge*16);
      float4 a=p[0], b=p[1], c=p[2], d4=p[3];
      em[0]=a.x; em[1]=a.y; em[2]=a.z; em[3]=a.w;
      em[4]=b.x; em[5]=b.y; em[6]=b.z; em[7]=b.w;
      em[8]=c.x; em[9]=c.y; em[10]=c.z; em[11]=c.w;
      em[12]=d4.x; em[13]=d4.y; em[14]=d4.z; em[15]=d4.w;
    } else {
      const uint4* p = (const uint4*)((const ushort*)emb + ge*16);
      uint4 a=p[0], b=p[1];
      em[0]=lo16(a.x); em[1]=hi16(a.x); em[2]=lo16(a.y); em[3]=hi16(a.y);
      em[4]=lo16(a.z); em[5]=hi16(a.z); em[6]=lo16(a.w); em[7]=hi16(a.w);
      em[8]=lo16(b.x); em[9]=hi16(b.x); em[10]=lo16(b.y); em[11]=hi16(b.y);
      em[12]=lo16(b.z); em[13]=hi16(b.z); em[14]=lo16(b.w); em[15]=hi16(b.w);
    }
    #pragma unroll
    for (int cc=0; cc<2; ++cc){
      const int c = r + cc*32;
      float ak = ldf<F32>(bk1, c), av = ldf<F32>(bv1, c);
      #pragma unroll
      for (int b=0; b<16; ++b){
        ak += em[b] * ldf<F32>(Wk1, b*64 + c);
        av += em[b] * ldf<F32>(Wv1, b*64 + c);
      }
      sm.hidA[0][le][c] = f2b(siluf(ak));
      sm.hidA[1][le][c] = f2b(siluf(av));
    }
  }
  __syncthreads();

  // Phase C: kv-outer (K then V), 40-reg accumulators, unroll-4 tile loops
  const int h = t >> 6;
  const int lane = t & 63, q = lane >> 4, n = lane & 15;
  const float invfan = 0.14433756729740643f;   // 1/sqrt(48)
  float exv[2][4];

  #pragma unroll 1
  for (int kv=0; kv<2; ++kv){
    const ushort* wmat = W2T + (size_t)kv*147456;
    const void* bvec = kv ? bv2 : bk2;
    bf16x8 af[2][2];
    #pragma unroll
    for (int Mt=0; Mt<2; ++Mt)
      #pragma unroll
      for (int kh=0; kh<2; ++kh)
        af[Mt][kh] = *(const bf16x8*)&sm.hidA[kv][Mt*16+n][kh*32 + q*8];

    float a0[2][4], aP[2][4], aW[3][2][4];
    #pragma unroll
    for (int Mt=0; Mt<2; ++Mt)
      #pragma unroll
      for (int z=0; z<4; ++z){
        a0[Mt][z]=0.f; aP[Mt][z]=0.f;
        aW[0][Mt][z]=0.f; aW[1][Mt][z]=0.f; aW[2][Mt][z]=0.f;
      }

    // ss tiles 0..15 + vv tiles 16..23 -> a0
    #pragma unroll 4
    for (int tl=0; tl<24; ++tl){
      const size_t tb = ((size_t)((h*36+tl)*16 + n))*64 + q*8;
      bf16x8 b0 = *(const bf16x8*)(wmat + tb), b1 = *(const bf16x8*)(wmat + tb + 32);
      const float bb = ldf<F32>(bvec, h*576 + tl*16 + n);
      const bool ss = (tl < 16);
      const int u = ss ? (tl*2 + (n>>3)) : ((tl-16)*2 + (n>>3));
      #pragma unroll
      for (int Mt=0; Mt<2; ++Mt){
        f32x4 fv = ss ? *(const f32x4*)&sm.u.f.fssT[u][Mt*16+q*4]
                      : *(const f32x4*)&sm.u.f.fvvT[u][Mt*16+q*4];
        f32x4 c = {bb,bb,bb,bb};
        c = __builtin_amdgcn_mfma_f32_16x16x32_bf16(af[Mt][0], b0, c, 0,0,0);
        c = __builtin_amdgcn_mfma_f32_16x16x32_bf16(af[Mt][1], b1, c, 0,0,0);
        #pragma unroll
        for (int z=0; z<4; ++z) a0[Mt][z] += c[z]*fv[z];
      }
    }
    // sv tiles 24..31 -> aP
    #pragma unroll 4
    for (int tl=24; tl<32; ++tl){
      const size_t tb = ((size_t)((h*36+tl)*16 + n))*64 + q*8;
      bf16x8 b0 = *(const bf16x8*)(wmat + tb), b1 = *(const bf16x8*)(wmat + tb + 32);
      const float bb = ldf<F32>(bvec, h*576 + tl*16 + n);
      const int u = (tl-24)*4 + (n>>2);
      #pragma unroll
      for (int Mt=0; Mt<2; ++Mt){
        f32x4 fv = *(const f32x4*)&sm.u.f.sslT[u][Mt*16+q*4];
        f32x4 c = {bb,bb,bb,bb};
        c = __builtin_amdgcn_mfma_f32_16x16x32_bf16(af[Mt][0], b0, c, 0,0,0);
        c = __builtin_amdgcn_mfma_f32_16x16x32_bf16(af[Mt][1], b1, c, 0,0,0);
        #pragma unroll
        for (int z=0; z<4; ++z) aP[Mt][z] += c[z]*fv[z];
      }
    }
    // vs tiles 32..35 -> aW[i]
    #pragma unroll
    for (int tl=32; tl<36; ++tl){
      const size_t tb = ((size_t)((h*36+tl)*16 + n))*64 + q*8;
      bf16x8 b0 = *(const bf16x8*)(wmat + tb), b1 = *(const bf16x8*)(wmat + tb + 32);
      const float bb = ldf<F32>(bvec, h*576 + tl*16 + n);
      const int u = (tl-32)*4 + (n>>2);
      #pragma unroll
      for (int Mt=0; Mt<2; ++Mt){
        f32x4 c = {bb,bb,bb,bb};
        c = __builtin_amdgcn_mfma_f32_16x16x32_bf16(af[Mt][0], b0, c, 0,0,0);
        c = __builtin_amdgcn_mfma_f32_16x16x32_bf16(af[Mt][1], b1, c, 0,0,0);
        #pragma unroll
        for (int i=0; i<3; ++i){
          f32x4 fv = *(const f32x4*)&sm.vshT[u][i][Mt*16+q*4];
          #pragma unroll
          for (int z=0; z<4; ++z) aW[i][Mt][z] += c[z]*fv[z];
        }
      }
    }

    // cross-lane u-reductions
    #pragma unroll
    for (int Mt=0; Mt<2; ++Mt)
      #pragma unroll
      for (int z=0; z<4; ++z){
        a0[Mt][z] += __shfl_xor(a0[Mt][z], 8, 64);
        aP[Mt][z] += __shfl_xor(aP[Mt][z], 4, 64);
        aP[Mt][z] += __shfl_xor(aP[Mt][z], 8, 64);
        #pragma unroll
        for (int i=0; i<3; ++i){
          aW[i][Mt][z] += __shfl_xor(aW[i][Mt][z], 4, 64);
          aW[i][Mt][z] += __shfl_xor(aW[i][Mt][z], 8, 64);
        }
      }

    if (kv == 0){
      // logits from K results -> exv (kept in registers across kv=1)
      float lgp[2][4];
      #pragma unroll
      for (int Mt=0; Mt<2; ++Mt)
        #pragma unroll
        for (int z=0; z<4; ++z){
          const int el = Mt*16 + q*4 + z;
          const int d = sm.dstL[el];
          float acc = 0.f;
          if (n < 8) acc = qt0g[d*32 + h*8 + n] * a0[Mt][z];
          if (n < 4){
            float s = 0.f;
            #pragma unroll
            for (int i=0; i<3; ++i){
              float k1 = aP[Mt][z]*sm.sh1T[i][el] + aW[i][Mt][z];
              s += qt1g[d*48 + h*12 + n*3 + i] * k1;
            }
            acc += s * 0.5773502691896258f;
          }
          lgp[Mt][z] = acc;
        }
      #pragma unroll
      for (int Mt=0; Mt<2; ++Mt)
        #pragma unroll
        for (int z=0; z<4; ++z){
          lgp[Mt][z] += __shfl_xor(lgp[Mt][z], 1, 64);
          lgp[Mt][z] += __shfl_xor(lgp[Mt][z], 2, 64);
          lgp[Mt][z] += __shfl_xor(lgp[Mt][z], 4, 64);
          lgp[Mt][z] += __shfl_xor(lgp[Mt][z], 8, 64);
          float lg = lgp[Mt][z] * invfan * 0.025f;   // 1/(sqrt(80)*sqrt(20))
          lg = fminf(10.f, fmaxf(-10.f, lg));
          exv[Mt][z] = __expf(lg - 10.0f);           // fixed softmax max = 10 (clipped logits)
        }
    } else {
      // V results -> cont staging (cont overlays feature arrays; barrier: all waves
      // must be done READING fss/fvv/ssl in their kv=1 loops before any write)
      __syncthreads();
      #pragma unroll
      for (int Mt=0; Mt<2; ++Mt)
        #pragma unroll
        for (int z=0; z<4; ++z){
          const int el = Mt*16 + q*4 + z;
          const float ex = exv[Mt][z];
          if (n == 0) sm.u.cont[h][el][0] = ex;
          if (n < 8)  sm.u.cont[h][el][1+n] = ex * a0[Mt][z] * invfan;
          if (n < 4){
            #pragma unroll
            for (int i=0; i<3; ++i){
              float v1 = (aP[Mt][z]*sm.sh1T[i][el] + aW[i][Mt][z]) * invfan;
              sm.u.cont[h][el][9+n*3+i] = ex * v1;
            }
          }
        }
    }
  }
  __syncthreads();

  // segmented reduction over dst-sorted edges -> few atomics
  if (t < 84){
    const int h2 = t / 21, comp = t - h2*21;
    float acc = 0.f;
    #pragma unroll 1
    for (int e2=0; e2<32; ++e2){
      acc += sm.u.cont[h2][e2][comp];
      const int d2 = sm.dstL[e2];
      if (e2 == 31 || sm.dstL[e2+1] != d2){
        if (comp == 0)      atomicAdd(denom + d2*4  + h2, acc);
        else if (comp < 9)  atomicAdd(agg0  + d2*32 + h2*8  + (comp-1), acc);
        else                atomicAdd(agg1  + d2*48 + h2*12 + (comp-9), acc);
        acc = 0.f;
      }
    }
  }
}

__global__ __launch_bounds__(256) void edge_kernel(
    const void* nf, const int* eidx, const int* eord, const void* esh, const void* emb,
    const void* Wk1, const void* bk1, const void* bk2,
    const void* Wv1, const void* bv1, const void* bv2,
    const ushort* W2T, const float* qt0g, const float* qt1g,
    float* agg0, float* agg1, float* denom, const int* flag){
  __shared__ Smem sm;
  if (*flag)
    edge_body<true >(nf,eidx,eord,esh,emb,Wk1,bk1,bk2,Wv1,bv1,bv2,W2T,qt0g,qt1g,agg0,agg1,denom,sm);
  else
    edge_body<false>(nf,eidx,eord,esh,emb,Wk1,bk1,bk2,Wv1,bv1,bv2,W2T,qt0g,qt1g,agg0,agg1,denom,sm);
}

// ---------- K4: per-node output MLP ----------
__global__ __launch_bounds__(64) void node_out_kernel(
    const void* __restrict__ nf, const float* __restrict__ agg0r, const float* __restrict__ agg1r,
    const float* __restrict__ denom,
    const void* __restrict__ Wo0, const void* __restrict__ Wo1,
    const void* __restrict__ Wf10, const void* __restrict__ Wf11,
    const void* __restrict__ Wf20, const void* __restrict__ Wf21,
    void* __restrict__ out, const int* __restrict__ flag){
  __shared__ float ag0[32], ag1[48], adiv[4];
  __shared__ float x0s[32], x1s[48], a0s[64], f1s[48], coefs[16];
  const bool F32 = (*flag) != 0;
  const int n = blockIdx.x, t = threadIdx.x;
  if (t < 4) adiv[t] = 1.f / (denom[n*4+t] + 1e-12f);
  __syncthreads();
  if (t < 32) ag0[t] = agg0r[n*32+t] * adiv[t>>3];
  if (t < 48) ag1[t] = agg1r[n*48+t] * adiv[t/12];
  __syncthreads();
  if (t < 32){
    float o = 0.f;
    #pragma unroll
    for (int k=0; k<32; ++k) o += ag0[k]*ldfr(Wo0, k*32+t, F32);
    x0s[t] = ldfr(nf, n*80+t, F32) + o*0.17677669529663687f;
  }
  if (t < 48){
    int w = t/3, i = t - w*3;
    float o = 0.f;
    #pragma unroll
    for (int u=0; u<16; ++u) o += ag1[u*3+i]*ldfr(Wo1, u*16+w, F32);
    x1s[t] = ldfr(nf, n*80+32+t, F32) + o*0.25f;
  }
  __syncthreads();
  {
    float f0 = 0.f;
    #pragma unroll
    for (int u=0; u<32; ++u) f0 += x0s[u]*ldfr(Wf10, u*64+t, F32);
    a0s[t] = siluf(f0*0.17677669529663687f);
  }
  if (t < 48){
    int w = t/3, i = t - w*3;
    float f1 = 0.f;
    #pragma unroll
    for (int u=0; u<16; ++u) f1 += x1s[u*3+i]*ldfr(Wf11, u*16+w, F32);
    f1s[t] = f1*0.25f;
  }
  __syncthreads();
  if (t < 16){
    float a = f1s[t*3], b = f1s[t*3+1], c = f1s[t*3+2];
    float nrm = sqrtf(a*a+b*b+c*c);
    float safe = fmaxf(nrm, 1e-8f);
    coefs[t] = (nrm < 1e-8f) ? 0.f : siluf(nrm)/safe;
  }
  __syncthreads();
  if (t < 32){
    float g = 0.f;
    #pragma unroll
    for (int u=0; u<64; ++u) g += a0s[u]*ldfr(Wf20, u*32+t, F32);
    float val = x0s[t] + g*0.125f;
    if (F32) ((float*)out)[n*80+t] = val; else ((ushort*)out)[n*80+t] = f2b(val);
  }
  if (t < 48){
    int w = t/3, i = t - w*3;
    float g = 0.f;
    #pragma unroll
    for (int u=0; u<16; ++u) g += coefs[u]*f1s[u*3+i]*ldfr(Wf21, u*16+w, F32);
    float val = x1s[t] + g*0.25f;
    if (F32) ((float*)out)[n*80+32+t] = val; else ((ushort*)out)[n*80+32+t] = f2b(val);
  }
}

extern "C" void kernel_launch(void* const* d_in, const int* in_sizes, int n_in,
                              void* d_out, int out_size, void* d_ws, size_t ws_size,
                              hipStream_t stream){
  const void* nf   = d_in[0];
  const int*  eidx = (const int*)d_in[1];
  const void* esh  = d_in[2];
  const void* emb  = d_in[3];
  const void* Wq0  = d_in[4];
  const void* Wq1  = d_in[5];
  const void* Wk1  = d_in[6];
  const void* bk1  = d_in[7];
  const void* Wk2  = d_in[8];
  const void* bk2  = d_in[9];
  const void* Wv1  = d_in[10];
  const void* bv1  = d_in[11];
  const void* Wv2  = d_in[12];
  const void* bv2  = d_in[13];
  const void* Wd0  = d_in[14];
  const void* Wd1  = d_in[15];
  const void* Wo0  = d_in[16];
  const void* Wo1  = d_in[17];
  const void* Wf10 = d_in[18];
  const void* Wf11 = d_in[19];
  const void* Wf20 = d_in[20];
  const void* Wf21 = d_in[21];
  float* ws = (float*)d_ws;

  float* agg0  = ws + OFF_AGG0;
  float* agg1  = ws + OFF_AGG1;
  float* denom = ws + OFF_DEN;
  int*   cnt   = (int*)(ws + OFF_CNT);
  int*   flag  = (int*)(ws + OFF_FLAG);
  ushort* W2T  = (ushort*)(ws + OFF_W2T);
  float* qt0   = ws + OFF_QT0;
  float* qt1   = ws + OFF_QT1;
  int*   eord  = (int*)(ws + OFF_EORD);

  hipMemsetAsync(agg0, 0, 170000*sizeof(float), stream);
  prep_kernel<<<229, 256, 0, stream>>>(nf, eidx, Wk2, Wv2, Wq0, Wq1, Wd0, Wd1,
                                       W2T, qt0, qt1, cnt, flag);
  scan_kernel<<<1, 256, 0, stream>>>(cnt);
  scat_kernel<<<125, 256, 0, stream>>>(eidx, cnt, eord);
  edge_kernel<<<N_EDGES/32, 256, 0, stream>>>(nf, eidx, eord, esh, emb,
                                              Wk1, bk1, bk2, Wv1, bv1, bv2,
                                              W2T, qt0, qt1,
                                              agg0, agg1, denom, flag);
  node_out_kernel<<<N_NODES, 64, 0, stream>>>(nf, agg0, agg1, denom,
                                              Wo0, Wo1, Wf10, Wf11, Wf20, Wf21, d_out, flag);
}